// Round 1
// baseline (1714.550 us; speedup 1.0000x reference)
//
#include <hip/hip_runtime.h>
#include <math.h>

#define HN 128
#define NC 8
#define EPSV 1e-5f
#define SLOPEV 0.01f

// ---------------- degree count (int atomics, exact) ----------------
__global__ void deg_kernel(const int* __restrict__ src, const int* __restrict__ dst,
                           int* __restrict__ degO, int* __restrict__ degI, int E) {
    int e = blockIdx.x * blockDim.x + threadIdx.x;
    if (e < E) {
        atomicAdd(&degO[src[e]], 1);
        atomicAdd(&degI[dst[e]], 1);
    }
}

// ---------------- exclusive scan of in-degrees -> row_ptr, cursor ----------------
#define SCAN_BDIM 1024
#define SCAN_VPT 16
__global__ void scan_kernel(const int* __restrict__ degI, int* __restrict__ row_ptr,
                            int* __restrict__ cursor, int n) {
    __shared__ int sSums[SCAN_BDIM];
    __shared__ int sCarry;
    int tid = threadIdx.x;
    if (tid == 0) sCarry = 0;
    __syncthreads();
    const int CHUNK = SCAN_BDIM * SCAN_VPT;
    for (int base = 0; base < n; base += CHUNK) {
        int i0 = base + tid * SCAN_VPT;
        int vals[SCAN_VPT];
        int tot = 0;
        #pragma unroll
        for (int j = 0; j < SCAN_VPT; j++) {
            int idx = i0 + j;
            int v = (idx < n) ? degI[idx] : 0;
            vals[j] = tot;           // exclusive within-thread
            tot += v;
        }
        sSums[tid] = tot;
        __syncthreads();
        // Hillis-Steele inclusive scan over thread totals
        for (int off = 1; off < SCAN_BDIM; off <<= 1) {
            int t = (tid >= off) ? sSums[tid - off] : 0;
            __syncthreads();
            sSums[tid] += t;
            __syncthreads();
        }
        int threadBase = sCarry + sSums[tid] - tot;   // exclusive across threads
        #pragma unroll
        for (int j = 0; j < SCAN_VPT; j++) {
            int idx = i0 + j;
            if (idx < n) {
                int rp = threadBase + vals[j];
                row_ptr[idx] = rp;
                cursor[idx] = rp;
            }
        }
        __syncthreads();
        if (tid == 0) sCarry += sSums[SCAN_BDIM - 1];
        __syncthreads();
    }
    if (threadIdx.x == 0) row_ptr[n] = sCarry;
}

// ---------------- norms: clamp(deg,1)^-0.5 ----------------
__global__ void norm_kernel(const int* __restrict__ degO, const int* __restrict__ degI,
                            float* __restrict__ onorm, float* __restrict__ inorm, int n) {
    int i = blockIdx.x * blockDim.x + threadIdx.x;
    if (i < n) {
        float a = (float)degO[i]; if (a < 1.f) a = 1.f;
        float b = (float)degI[i]; if (b < 1.f) b = 1.f;
        onorm[i] = rsqrtf(a);
        inorm[i] = rsqrtf(b);
    }
}

// ---------------- CSR edge-id scatter ----------------
__global__ void eid_scatter(const int* __restrict__ dst, int* __restrict__ cursor,
                            int* __restrict__ eids, int E) {
    int e = blockIdx.x * blockDim.x + threadIdx.x;
    if (e < E) {
        int p = atomicAdd(&cursor[dst[e]], 1);
        eids[p] = e;
    }
}

// ---------------- aggregation: one wave per dst node ----------------
// out[i,:] = in_norm[i] * sum_{e: dst[e]=i} out_norm[src[e]] * x[src[e],:]
__global__ __launch_bounds__(256) void agg_kernel(
        const float* __restrict__ x, float* __restrict__ out,
        const int* __restrict__ src, const int* __restrict__ eids,
        const int* __restrict__ row_ptr,
        const float* __restrict__ onorm, const float* __restrict__ inorm, int n) {
    int node = blockIdx.x * 4 + (threadIdx.x >> 6);
    if (node >= n) return;
    int lane = threadIdx.x & 63;
    int rp0 = row_ptr[node], rp1 = row_ptr[node + 1];
    float accx = 0.f, accy = 0.f;
    int j = rp0;
    for (; j + 1 < rp1; j += 2) {    // 2-edge unroll for load ILP
        int e0 = eids[j], e1 = eids[j + 1];
        int s0 = src[e0], s1 = src[e1];
        float w0 = onorm[s0], w1 = onorm[s1];
        const float2 v0 = *(const float2*)(x + (size_t)s0 * HN + lane * 2);
        const float2 v1 = *(const float2*)(x + (size_t)s1 * HN + lane * 2);
        accx += w0 * v0.x + w1 * v1.x;
        accy += w0 * v0.y + w1 * v1.y;
    }
    if (j < rp1) {
        int e0 = eids[j];
        int s0 = src[e0];
        float w0 = onorm[s0];
        const float2 v0 = *(const float2*)(x + (size_t)s0 * HN + lane * 2);
        accx += w0 * v0.x;
        accy += w0 * v0.y;
    }
    float wi = inorm[node];
    float2 o; o.x = accx * wi; o.y = accy * wi;
    *(float2*)(out + (size_t)node * HN + lane * 2) = o;
}

// ---------------- GEMM [n,128]@[128,128]+b, optional col-stats / lrelu ----------------
// block: 256 threads -> 64 rows x 128 cols; thread = 4 rows x 8 cols
template<int DO_STATS, int DO_LRELU>
__global__ __launch_bounds__(256) void gemm_kernel(
        const float* __restrict__ A, const float* __restrict__ W,
        const float* __restrict__ bias, float* __restrict__ out,
        float* __restrict__ colsum, float* __restrict__ colsq, int n) {
    __shared__ float sA[64 * 132];   // +4 pad: 2-way LDS aliasing only (free)
    int tid = threadIdx.x;
    int row0 = blockIdx.x * 64;
    for (int i = tid; i < 64 * 32; i += 256) {
        int r = i >> 5, c4 = (i & 31) << 2;
        float4 v;
        if (row0 + r < n) v = *(const float4*)(A + (size_t)(row0 + r) * HN + c4);
        else v = make_float4(0.f, 0.f, 0.f, 0.f);
        *(float4*)&sA[r * 132 + c4] = v;
    }
    __syncthreads();
    int rowg = tid >> 4, colg = tid & 15;
    int rb = rowg * 4, cb = colg * 8;
    float acc[4][8];
    #pragma unroll
    for (int r = 0; r < 4; r++)
        #pragma unroll
        for (int c = 0; c < 8; c++) acc[r][c] = 0.f;

    for (int k = 0; k < HN; k += 4) {
        float4 a4[4];
        #pragma unroll
        for (int r = 0; r < 4; r++) a4[r] = *(const float4*)&sA[(rb + r) * 132 + k];
        #pragma unroll
        for (int kk = 0; kk < 4; kk++) {
            float4 wlo = *(const float4*)(W + (size_t)(k + kk) * HN + cb);
            float4 whi = *(const float4*)(W + (size_t)(k + kk) * HN + cb + 4);
            float wv[8] = {wlo.x, wlo.y, wlo.z, wlo.w, whi.x, whi.y, whi.z, whi.w};
            #pragma unroll
            for (int r = 0; r < 4; r++) {
                float av = ((const float*)&a4[r])[kk];
                #pragma unroll
                for (int c = 0; c < 8; c++) acc[r][c] = fmaf(av, wv[c], acc[r][c]);
            }
        }
    }

    float bv[8];
    #pragma unroll
    for (int c = 0; c < 8; c++) bv[c] = bias[cb + c];
    float cs[8], cq[8];
    #pragma unroll
    for (int c = 0; c < 8; c++) { cs[c] = 0.f; cq[c] = 0.f; }

    #pragma unroll
    for (int r = 0; r < 4; r++) {
        int row = row0 + rb + r;
        if (row < n) {
            float v[8];
            #pragma unroll
            for (int c = 0; c < 8; c++) {
                float t = acc[r][c] + bv[c];
                if (DO_LRELU) t = (t >= 0.f) ? t : SLOPEV * t;
                v[c] = t;
                if (DO_STATS) { cs[c] += t; cq[c] += t * t; }
            }
            *(float4*)(out + (size_t)row * HN + cb)     = make_float4(v[0], v[1], v[2], v[3]);
            *(float4*)(out + (size_t)row * HN + cb + 4) = make_float4(v[4], v[5], v[6], v[7]);
        }
    }

    if (DO_STATS) {
        // block-level reduce in LDS (reuse sA), then 2 atomics per col per block
        __syncthreads();
        float* redsum = sA;
        float* redsq  = sA + 2048;
        #pragma unroll
        for (int c = 0; c < 8; c++) {
            redsum[(cb + c) * 16 + rowg] = cs[c];
            redsq [(cb + c) * 16 + rowg] = cq[c];
        }
        __syncthreads();
        if (tid < HN) {
            float s = 0.f, q = 0.f;
            #pragma unroll
            for (int j = 0; j < 16; j++) { s += redsum[tid * 16 + j]; q += redsq[tid * 16 + j]; }
            atomicAdd(&colsum[tid], s);
            atomicAdd(&colsq[tid], q);
        }
    }
}

// ---------------- BN finalize: per-col scale/shift ----------------
__global__ void bn_finalize(const float* __restrict__ colsum, const float* __restrict__ colsq,
                            const float* __restrict__ gamma, const float* __restrict__ beta,
                            float* __restrict__ scale, float* __restrict__ shift, int n) {
    int c = threadIdx.x;
    if (c < HN) {
        float inv = 1.f / (float)n;
        float mean = colsum[c] * inv;
        float var = colsq[c] * inv - mean * mean;
        if (var < 0.f) var = 0.f;
        float s = gamma[c] * rsqrtf(var + EPSV);
        scale[c] = s;
        shift[c] = beta[c] - mean * s;
    }
}

// ---------------- BN apply + lrelu (elementwise, float4) ----------------
__global__ __launch_bounds__(256) void bn_apply(
        const float* __restrict__ in, float* __restrict__ out,
        const float* __restrict__ scale, const float* __restrict__ shift, int total4) {
    int i = blockIdx.x * blockDim.x + threadIdx.x;
    if (i >= total4) return;
    int cp = (i & 31) << 2;   // 32 float4 per row of 128
    float4 v = ((const float4*)in)[i];
    float4 s = *(const float4*)(scale + cp);
    float4 t = *(const float4*)(shift + cp);
    float4 h;
    h.x = fmaf(v.x, s.x, t.x); h.x = (h.x >= 0.f) ? h.x : SLOPEV * h.x;
    h.y = fmaf(v.y, s.y, t.y); h.y = (h.y >= 0.f) ? h.y : SLOPEV * h.y;
    h.z = fmaf(v.z, s.z, t.z); h.z = (h.z >= 0.f) ? h.z : SLOPEV * h.z;
    h.w = fmaf(v.w, s.w, t.w); h.w = (h.w >= 0.f) ? h.w : SLOPEV * h.w;
    ((float4*)out)[i] = h;
}

// ---------------- classifier: [n,128]@[128,8]+bc ----------------
__global__ __launch_bounds__(256) void classifier_kernel(
        const float* __restrict__ A, const float* __restrict__ Wc,
        const float* __restrict__ bc, float* __restrict__ out, int n) {
    __shared__ float sW[HN * NC];
    __shared__ float sA[32 * 132];
    int tid = threadIdx.x;
    for (int i = tid; i < HN * NC; i += 256) sW[i] = Wc[i];
    int row0 = blockIdx.x * 32;
    for (int i = tid; i < 32 * 32; i += 256) {
        int r = i >> 5, c4 = (i & 31) << 2;
        float4 v = (row0 + r < n) ? *(const float4*)(A + (size_t)(row0 + r) * HN + c4)
                                  : make_float4(0.f, 0.f, 0.f, 0.f);
        *(float4*)&sA[r * 132 + c4] = v;
    }
    __syncthreads();
    int r = tid >> 3, c = tid & 7;
    float acc = 0.f;
    #pragma unroll 8
    for (int k = 0; k < HN; k++) acc = fmaf(sA[r * 132 + k], sW[k * NC + c], acc);
    int row = row0 + r;
    if (row < n) out[(size_t)row * NC + c] = acc + bc[c];
}

extern "C" void kernel_launch(void* const* d_in, const int* in_sizes, int n_in,
                              void* d_out, int out_size, void* d_ws, size_t ws_size,
                              hipStream_t stream) {
    const float* node_feat = (const float*)d_in[0];
    const int*   src    = (const int*)d_in[1];
    const int*   dst    = (const int*)d_in[2];
    const float* W1     = (const float*)d_in[3];
    const float* b1     = (const float*)d_in[4];
    const float* W2     = (const float*)d_in[5];
    const float* b2     = (const float*)d_in[6];
    const float* gamma1 = (const float*)d_in[7];
    const float* beta1  = (const float*)d_in[8];
    const float* gamma2 = (const float*)d_in[9];
    const float* beta2  = (const float*)d_in[10];
    const float* Wn1    = (const float*)d_in[11];
    const float* bn1    = (const float*)d_in[12];
    const float* Wn2    = (const float*)d_in[13];
    const float* bn2    = (const float*)d_in[14];
    const float* Wc     = (const float*)d_in[15];
    const float* bc     = (const float*)d_in[16];
    float* out = (float*)d_out;

    const int N = in_sizes[0] / HN;
    const int E = in_sizes[1];

    char* p = (char*)d_ws;
    float* bufA  = (float*)p; p += (size_t)N * HN * 4;
    float* bufB  = (float*)p; p += (size_t)N * HN * 4;
    float* onorm = (float*)p; p += (size_t)N * 4;
    float* inorm = (float*)p; p += (size_t)N * 4;
    float* scale = (float*)p; p += HN * 4;
    float* shift = (float*)p; p += HN * 4;
    char* zbase = p;
    float* cs1 = (float*)p; p += HN * 4;
    float* cq1 = (float*)p; p += HN * 4;
    float* cs2 = (float*)p; p += HN * 4;
    float* cq2 = (float*)p; p += HN * 4;
    int* degO = (int*)p; p += (size_t)N * 4;
    int* degI = (int*)p; p += (size_t)N * 4;
    size_t zbytes = (size_t)(p - zbase);
    int* row_ptr = (int*)p; p += (size_t)(N + 1) * 4;
    int* cursor  = (int*)p; p += (size_t)N * 4;
    int* eids    = (int*)p; p += (size_t)E * 4;
    if ((size_t)(p - (char*)d_ws) > ws_size) return;   // ws too small: bail loudly

    hipMemsetAsync(zbase, 0, zbytes, stream);

    int gE = (E + 255) / 256, gN = (N + 255) / 256;
    deg_kernel<<<gE, 256, 0, stream>>>(src, dst, degO, degI, E);
    scan_kernel<<<1, SCAN_BDIM, 0, stream>>>(degI, row_ptr, cursor, N);
    norm_kernel<<<gN, 256, 0, stream>>>(degO, degI, onorm, inorm, N);
    eid_scatter<<<gE, 256, 0, stream>>>(dst, cursor, eids, E);

    int gAgg = (N + 3) / 4;
    int gGemm = (N + 63) / 64;
    int gApply = (N * 32 + 255) / 256;

    // Layer 1: conv1 + bn1 + lrelu
    agg_kernel<<<gAgg, 256, 0, stream>>>(node_feat, bufA, src, eids, row_ptr, onorm, inorm, N);
    gemm_kernel<1, 0><<<gGemm, 256, 0, stream>>>(bufA, W1, b1, bufB, cs1, cq1, N);
    bn_finalize<<<1, 128, 0, stream>>>(cs1, cq1, gamma1, beta1, scale, shift, N);
    bn_apply<<<gApply, 256, 0, stream>>>(bufB, bufA, scale, shift, N * 32);

    // Layer 2: conv2 + bn2 + lrelu
    agg_kernel<<<gAgg, 256, 0, stream>>>(bufA, bufB, src, eids, row_ptr, onorm, inorm, N);
    gemm_kernel<1, 0><<<gGemm, 256, 0, stream>>>(bufB, W2, b2, bufA, cs2, cq2, N);
    bn_finalize<<<1, 128, 0, stream>>>(cs2, cq2, gamma2, beta2, scale, shift, N);
    bn_apply<<<gApply, 256, 0, stream>>>(bufA, bufB, scale, shift, N * 32);

    // Layer 3: convnode1 + lrelu (fused in epilogue)
    agg_kernel<<<gAgg, 256, 0, stream>>>(bufB, bufA, src, eids, row_ptr, onorm, inorm, N);
    gemm_kernel<0, 1><<<gGemm, 256, 0, stream>>>(bufA, Wn1, bn1, bufB, nullptr, nullptr, N);

    // Layer 4: convnode2 + lrelu
    agg_kernel<<<gAgg, 256, 0, stream>>>(bufB, bufA, src, eids, row_ptr, onorm, inorm, N);
    gemm_kernel<0, 1><<<gGemm, 256, 0, stream>>>(bufA, Wn2, bn2, bufB, nullptr, nullptr, N);

    // Classifier
    classifier_kernel<<<(N + 31) / 32, 256, 0, stream>>>(bufB, Wc, bc, out, N);
}

// Round 2
// 1301.062 us; speedup vs baseline: 1.3178x; 1.3178x over previous
//
#include <hip/hip_runtime.h>
#include <math.h>

#define HN 128
#define NC 8
#define EPSV 1e-5f
#define SLOPEV 0.01f

// ---------------- degree count (int atomics, exact) ----------------
__global__ void deg_kernel(const int* __restrict__ src, const int* __restrict__ dst,
                           int* __restrict__ degO, int* __restrict__ degI, int E) {
    int e = blockIdx.x * blockDim.x + threadIdx.x;
    if (e < E) {
        atomicAdd(&degO[src[e]], 1);
        atomicAdd(&degI[dst[e]], 1);
    }
}

// ---------------- exclusive scan of in-degrees -> row_ptr, cursor ----------------
#define SCAN_BDIM 1024
#define SCAN_VPT 16
__global__ void scan_kernel(const int* __restrict__ degI, int* __restrict__ row_ptr,
                            int* __restrict__ cursor, int n) {
    __shared__ int sSums[SCAN_BDIM];
    __shared__ int sCarry;
    int tid = threadIdx.x;
    if (tid == 0) sCarry = 0;
    __syncthreads();
    const int CHUNK = SCAN_BDIM * SCAN_VPT;
    for (int base = 0; base < n; base += CHUNK) {
        int i0 = base + tid * SCAN_VPT;
        int vals[SCAN_VPT];
        int tot = 0;
        #pragma unroll
        for (int j = 0; j < SCAN_VPT; j++) {
            int idx = i0 + j;
            int v = (idx < n) ? degI[idx] : 0;
            vals[j] = tot;
            tot += v;
        }
        sSums[tid] = tot;
        __syncthreads();
        for (int off = 1; off < SCAN_BDIM; off <<= 1) {
            int t = (tid >= off) ? sSums[tid - off] : 0;
            __syncthreads();
            sSums[tid] += t;
            __syncthreads();
        }
        int threadBase = sCarry + sSums[tid] - tot;
        #pragma unroll
        for (int j = 0; j < SCAN_VPT; j++) {
            int idx = i0 + j;
            if (idx < n) {
                int rp = threadBase + vals[j];
                row_ptr[idx] = rp;
                cursor[idx] = rp;
            }
        }
        __syncthreads();
        if (tid == 0) sCarry += sSums[SCAN_BDIM - 1];
        __syncthreads();
    }
    if (threadIdx.x == 0) row_ptr[n] = sCarry;
}

// ---------------- norms: clamp(deg,1)^-0.5 ----------------
__global__ void norm_kernel(const int* __restrict__ degO, const int* __restrict__ degI,
                            float* __restrict__ onorm, float* __restrict__ inorm, int n) {
    int i = blockIdx.x * blockDim.x + threadIdx.x;
    if (i < n) {
        float a = (float)degO[i]; if (a < 1.f) a = 1.f;
        float b = (float)degI[i]; if (b < 1.f) b = 1.f;
        onorm[i] = rsqrtf(a);
        inorm[i] = rsqrtf(b);
    }
}

// ---------------- CSR src-value scatter (one less indirection in agg) ----------------
__global__ void src_scatter(const int* __restrict__ src, const int* __restrict__ dst,
                            int* __restrict__ cursor, int* __restrict__ srcs, int E) {
    int e = blockIdx.x * blockDim.x + threadIdx.x;
    if (e < E) {
        int p = atomicAdd(&cursor[dst[e]], 1);
        srcs[p] = src[e];
    }
}

// ---------------- pack: fp32 features * onorm -> bf16 (RNE) ----------------
// total4 = N*32 float4s; row = i>>5
__global__ __launch_bounds__(256) void pack_kernel(
        const float* __restrict__ in, const float* __restrict__ onorm,
        ushort* __restrict__ out, int total4) {
    int i = blockIdx.x * blockDim.x + threadIdx.x;
    if (i >= total4) return;
    float w = onorm[i >> 5];
    float4 v = ((const float4*)in)[i];
    uint b[4];
    float vv[4] = {v.x * w, v.y * w, v.z * w, v.w * w};
    #pragma unroll
    for (int j = 0; j < 4; j++) {
        uint u = __float_as_uint(vv[j]);
        u = u + 0x7fffu + ((u >> 16) & 1u);   // RNE to bf16
        b[j] = u >> 16;
    }
    ushort4 o = make_ushort4((ushort)b[0], (ushort)b[1], (ushort)b[2], (ushort)b[3]);
    *(ushort4*)(out + (size_t)i * 4) = o;
}

// ---------------- aggregation: one wave per dst node, bf16 rows ----------------
// out[i,:] = in_norm[i] * sum_{p in row i} xb[srcs[p], :]   (onorm pre-folded)
__global__ __launch_bounds__(256) void agg_kernel(
        const uint* __restrict__ xb, float* __restrict__ out,
        const int* __restrict__ srcs, const int* __restrict__ row_ptr,
        const float* __restrict__ inorm, int n) {
    int node = blockIdx.x * 4 + (threadIdx.x >> 6);
    if (node >= n) return;
    int lane = threadIdx.x & 63;
    int rp0 = row_ptr[node], rp1 = row_ptr[node + 1];
    float accx = 0.f, accy = 0.f;
    int j = rp0;
    for (; j + 1 < rp1; j += 2) {
        int s0 = srcs[j], s1 = srcs[j + 1];
        uint u0 = xb[(size_t)s0 * 64 + lane];
        uint u1 = xb[(size_t)s1 * 64 + lane];
        accx += __uint_as_float(u0 << 16) + __uint_as_float(u1 << 16);
        accy += __uint_as_float(u0 & 0xffff0000u) + __uint_as_float(u1 & 0xffff0000u);
    }
    if (j < rp1) {
        uint u0 = xb[(size_t)srcs[j] * 64 + lane];
        accx += __uint_as_float(u0 << 16);
        accy += __uint_as_float(u0 & 0xffff0000u);
    }
    float wi = inorm[node];
    float2 o; o.x = accx * wi; o.y = accy * wi;
    *(float2*)(out + (size_t)node * HN + lane * 2) = o;
}

// ---------------- GEMM [n,128]@[128,128]+b, optional col-stats / lrelu ----------------
template<int DO_STATS, int DO_LRELU>
__global__ __launch_bounds__(256) void gemm_kernel(
        const float* __restrict__ A, const float* __restrict__ W,
        const float* __restrict__ bias, float* __restrict__ out,
        float* __restrict__ colsum, float* __restrict__ colsq, int n) {
    __shared__ float sA[64 * 132];
    int tid = threadIdx.x;
    int row0 = blockIdx.x * 64;
    for (int i = tid; i < 64 * 32; i += 256) {
        int r = i >> 5, c4 = (i & 31) << 2;
        float4 v;
        if (row0 + r < n) v = *(const float4*)(A + (size_t)(row0 + r) * HN + c4);
        else v = make_float4(0.f, 0.f, 0.f, 0.f);
        *(float4*)&sA[r * 132 + c4] = v;
    }
    __syncthreads();
    int rowg = tid >> 4, colg = tid & 15;
    int rb = rowg * 4, cb = colg * 8;
    float acc[4][8];
    #pragma unroll
    for (int r = 0; r < 4; r++)
        #pragma unroll
        for (int c = 0; c < 8; c++) acc[r][c] = 0.f;

    for (int k = 0; k < HN; k += 4) {
        float4 a4[4];
        #pragma unroll
        for (int r = 0; r < 4; r++) a4[r] = *(const float4*)&sA[(rb + r) * 132 + k];
        #pragma unroll
        for (int kk = 0; kk < 4; kk++) {
            float4 wlo = *(const float4*)(W + (size_t)(k + kk) * HN + cb);
            float4 whi = *(const float4*)(W + (size_t)(k + kk) * HN + cb + 4);
            float wv[8] = {wlo.x, wlo.y, wlo.z, wlo.w, whi.x, whi.y, whi.z, whi.w};
            #pragma unroll
            for (int r = 0; r < 4; r++) {
                float av = ((const float*)&a4[r])[kk];
                #pragma unroll
                for (int c = 0; c < 8; c++) acc[r][c] = fmaf(av, wv[c], acc[r][c]);
            }
        }
    }

    float bv[8];
    #pragma unroll
    for (int c = 0; c < 8; c++) bv[c] = bias[cb + c];
    float cs[8], cq[8];
    #pragma unroll
    for (int c = 0; c < 8; c++) { cs[c] = 0.f; cq[c] = 0.f; }

    #pragma unroll
    for (int r = 0; r < 4; r++) {
        int row = row0 + rb + r;
        if (row < n) {
            float v[8];
            #pragma unroll
            for (int c = 0; c < 8; c++) {
                float t = acc[r][c] + bv[c];
                if (DO_LRELU) t = (t >= 0.f) ? t : SLOPEV * t;
                v[c] = t;
                if (DO_STATS) { cs[c] += t; cq[c] += t * t; }
            }
            *(float4*)(out + (size_t)row * HN + cb)     = make_float4(v[0], v[1], v[2], v[3]);
            *(float4*)(out + (size_t)row * HN + cb + 4) = make_float4(v[4], v[5], v[6], v[7]);
        }
    }

    if (DO_STATS) {
        __syncthreads();
        float* redsum = sA;
        float* redsq  = sA + 2048;
        #pragma unroll
        for (int c = 0; c < 8; c++) {
            redsum[(cb + c) * 16 + rowg] = cs[c];
            redsq [(cb + c) * 16 + rowg] = cq[c];
        }
        __syncthreads();
        if (tid < HN) {
            float s = 0.f, q = 0.f;
            #pragma unroll
            for (int j = 0; j < 16; j++) { s += redsum[tid * 16 + j]; q += redsq[tid * 16 + j]; }
            atomicAdd(&colsum[tid], s);
            atomicAdd(&colsq[tid], q);
        }
    }
}

// ---------------- BN finalize: per-col scale/shift ----------------
__global__ void bn_finalize(const float* __restrict__ colsum, const float* __restrict__ colsq,
                            const float* __restrict__ gamma, const float* __restrict__ beta,
                            float* __restrict__ scale, float* __restrict__ shift, int n) {
    int c = threadIdx.x;
    if (c < HN) {
        float inv = 1.f / (float)n;
        float mean = colsum[c] * inv;
        float var = colsq[c] * inv - mean * mean;
        if (var < 0.f) var = 0.f;
        float s = gamma[c] * rsqrtf(var + EPSV);
        scale[c] = s;
        shift[c] = beta[c] - mean * s;
    }
}

// ---------------- BN apply + lrelu (elementwise, float4) ----------------
__global__ __launch_bounds__(256) void bn_apply(
        const float* __restrict__ in, float* __restrict__ out,
        const float* __restrict__ scale, const float* __restrict__ shift, int total4) {
    int i = blockIdx.x * blockDim.x + threadIdx.x;
    if (i >= total4) return;
    int cp = (i & 31) << 2;
    float4 v = ((const float4*)in)[i];
    float4 s = *(const float4*)(scale + cp);
    float4 t = *(const float4*)(shift + cp);
    float4 h;
    h.x = fmaf(v.x, s.x, t.x); h.x = (h.x >= 0.f) ? h.x : SLOPEV * h.x;
    h.y = fmaf(v.y, s.y, t.y); h.y = (h.y >= 0.f) ? h.y : SLOPEV * h.y;
    h.z = fmaf(v.z, s.z, t.z); h.z = (h.z >= 0.f) ? h.z : SLOPEV * h.z;
    h.w = fmaf(v.w, s.w, t.w); h.w = (h.w >= 0.f) ? h.w : SLOPEV * h.w;
    ((float4*)out)[i] = h;
}

// ---------------- classifier: [n,128]@[128,8]+bc ----------------
__global__ __launch_bounds__(256) void classifier_kernel(
        const float* __restrict__ A, const float* __restrict__ Wc,
        const float* __restrict__ bc, float* __restrict__ out, int n) {
    __shared__ float sW[HN * NC];
    __shared__ float sA[32 * 132];
    int tid = threadIdx.x;
    for (int i = tid; i < HN * NC; i += 256) sW[i] = Wc[i];
    int row0 = blockIdx.x * 32;
    for (int i = tid; i < 32 * 32; i += 256) {
        int r = i >> 5, c4 = (i & 31) << 2;
        float4 v = (row0 + r < n) ? *(const float4*)(A + (size_t)(row0 + r) * HN + c4)
                                  : make_float4(0.f, 0.f, 0.f, 0.f);
        *(float4*)&sA[r * 132 + c4] = v;
    }
    __syncthreads();
    int r = tid >> 3, c = tid & 7;
    float acc = 0.f;
    #pragma unroll 8
    for (int k = 0; k < HN; k++) acc = fmaf(sA[r * 132 + k], sW[k * NC + c], acc);
    int row = row0 + r;
    if (row < n) out[(size_t)row * NC + c] = acc + bc[c];
}

extern "C" void kernel_launch(void* const* d_in, const int* in_sizes, int n_in,
                              void* d_out, int out_size, void* d_ws, size_t ws_size,
                              hipStream_t stream) {
    const float* node_feat = (const float*)d_in[0];
    const int*   src    = (const int*)d_in[1];
    const int*   dst    = (const int*)d_in[2];
    const float* W1     = (const float*)d_in[3];
    const float* b1     = (const float*)d_in[4];
    const float* W2     = (const float*)d_in[5];
    const float* b2     = (const float*)d_in[6];
    const float* gamma1 = (const float*)d_in[7];
    const float* beta1  = (const float*)d_in[8];
    const float* gamma2 = (const float*)d_in[9];
    const float* beta2  = (const float*)d_in[10];
    const float* Wn1    = (const float*)d_in[11];
    const float* bn1    = (const float*)d_in[12];
    const float* Wn2    = (const float*)d_in[13];
    const float* bn2    = (const float*)d_in[14];
    const float* Wc     = (const float*)d_in[15];
    const float* bc     = (const float*)d_in[16];
    float* out = (float*)d_out;

    const int N = in_sizes[0] / HN;
    const int E = in_sizes[1];

    char* p = (char*)d_ws;
    float* bufA  = (float*)p; p += (size_t)N * HN * 4;
    float* bufB  = (float*)p; p += (size_t)N * HN * 4;
    float* onorm = (float*)p; p += (size_t)N * 4;
    float* inorm = (float*)p; p += (size_t)N * 4;
    float* scale = (float*)p; p += HN * 4;
    float* shift = (float*)p; p += HN * 4;
    char* zbase = p;
    float* cs1 = (float*)p; p += HN * 4;
    float* cq1 = (float*)p; p += HN * 4;
    float* cs2 = (float*)p; p += HN * 4;
    float* cq2 = (float*)p; p += HN * 4;
    int* degO = (int*)p; p += (size_t)N * 4;
    int* degI = (int*)p; p += (size_t)N * 4;
    size_t zbytes = (size_t)(p - zbase);
    int* row_ptr = (int*)p; p += (size_t)(N + 1) * 4;
    int* cursor  = (int*)p; p += (size_t)N * 4;
    int* srcs    = (int*)p; p += (size_t)E * 4;
    if ((size_t)(p - (char*)d_ws) > ws_size) return;

    hipMemsetAsync(zbase, 0, zbytes, stream);

    int gE = (E + 255) / 256, gN = (N + 255) / 256;
    deg_kernel<<<gE, 256, 0, stream>>>(src, dst, degO, degI, E);
    scan_kernel<<<1, SCAN_BDIM, 0, stream>>>(degI, row_ptr, cursor, N);
    norm_kernel<<<gN, 256, 0, stream>>>(degO, degI, onorm, inorm, N);
    src_scatter<<<gE, 256, 0, stream>>>(src, dst, cursor, srcs, E);

    int gAgg = (N + 3) / 4;
    int gGemm = (N + 63) / 64;
    int gApply = (N * 32 + 255) / 256;

    // bf16 staging buffers alias dead fp32 ping-pong halves (see dataflow proof)
    ushort* HbB = (ushort*)bufB;   // layers 1-3: bufB dead at pack time
    ushort* HbA = (ushort*)bufA;   // layer 4: bufA dead at pack time

    // Layer 1: conv1 + bn1 + lrelu
    pack_kernel<<<gApply, 256, 0, stream>>>(node_feat, onorm, HbB, N * 32);
    agg_kernel<<<gAgg, 256, 0, stream>>>((const uint*)HbB, bufA, srcs, row_ptr, inorm, N);
    gemm_kernel<1, 0><<<gGemm, 256, 0, stream>>>(bufA, W1, b1, bufB, cs1, cq1, N);
    bn_finalize<<<1, 128, 0, stream>>>(cs1, cq1, gamma1, beta1, scale, shift, N);
    bn_apply<<<gApply, 256, 0, stream>>>(bufB, bufA, scale, shift, N * 32);

    // Layer 2: conv2 + bn2 + lrelu
    pack_kernel<<<gApply, 256, 0, stream>>>(bufA, onorm, HbB, N * 32);
    agg_kernel<<<gAgg, 256, 0, stream>>>((const uint*)HbB, bufA, srcs, row_ptr, inorm, N);
    gemm_kernel<1, 0><<<gGemm, 256, 0, stream>>>(bufA, W2, b2, bufB, cs2, cq2, N);
    bn_finalize<<<1, 128, 0, stream>>>(cs2, cq2, gamma2, beta2, scale, shift, N);
    bn_apply<<<gApply, 256, 0, stream>>>(bufB, bufA, scale, shift, N * 32);

    // Layer 3: convnode1 + lrelu (fused epilogue)
    pack_kernel<<<gApply, 256, 0, stream>>>(bufA, onorm, HbB, N * 32);
    agg_kernel<<<gAgg, 256, 0, stream>>>((const uint*)HbB, bufA, srcs, row_ptr, inorm, N);
    gemm_kernel<0, 1><<<gGemm, 256, 0, stream>>>(bufA, Wn1, bn1, bufB, nullptr, nullptr, N);

    // Layer 4: convnode2 + lrelu
    pack_kernel<<<gApply, 256, 0, stream>>>(bufB, onorm, HbA, N * 32);
    agg_kernel<<<gAgg, 256, 0, stream>>>((const uint*)HbA, bufB, srcs, row_ptr, inorm, N);
    gemm_kernel<0, 1><<<gGemm, 256, 0, stream>>>(bufB, Wn2, bn2, bufA, nullptr, nullptr, N);

    // Classifier
    classifier_kernel<<<(N + 31) / 32, 256, 0, stream>>>(bufA, Wc, bc, out, N);
}

// Round 3
// 1108.110 us; speedup vs baseline: 1.5473x; 1.1741x over previous
//
#include <hip/hip_runtime.h>
#include <math.h>

#define HN 128
#define NC 8
#define EPSV 1e-5f
#define SLOPEV 0.01f

// ---------------- degree count (int atomics, exact) ----------------
__global__ void deg_kernel(const int* __restrict__ src, const int* __restrict__ dst,
                           int* __restrict__ degO, int* __restrict__ degI, int E) {
    int e = blockIdx.x * blockDim.x + threadIdx.x;
    if (e < E) {
        atomicAdd(&degO[src[e]], 1);
        atomicAdd(&degI[dst[e]], 1);
    }
}

// ---------------- hierarchical exclusive scan (3 kernels) ----------------
// Stage A: per-block (1024-elem section) sums
__global__ __launch_bounds__(256) void scan_partial(const int* __restrict__ degI,
                                                    int* __restrict__ blockSums, int n) {
    __shared__ int sS[256];
    int tid = threadIdx.x;
    int base = blockIdx.x * 1024 + tid * 4;
    int s = 0;
    #pragma unroll
    for (int j = 0; j < 4; j++) {
        int idx = base + j;
        s += (idx < n) ? degI[idx] : 0;
    }
    sS[tid] = s;
    __syncthreads();
    for (int off = 128; off; off >>= 1) {
        if (tid < off) sS[tid] += sS[tid + off];
        __syncthreads();
    }
    if (tid == 0) blockSums[blockIdx.x] = sS[0];
}

// Stage B: single-block exclusive scan of block sums (nb <= 1024)
__global__ __launch_bounds__(1024) void scan_blocksums(int* __restrict__ blockSums, int nb) {
    __shared__ int sS[1024];
    int tid = threadIdx.x;
    int v = (tid < nb) ? blockSums[tid] : 0;
    sS[tid] = v;
    __syncthreads();
    for (int off = 1; off < 1024; off <<= 1) {
        int t = (tid >= off) ? sS[tid - off] : 0;
        __syncthreads();
        sS[tid] += t;
        __syncthreads();
    }
    if (tid < nb) blockSums[tid] = sS[tid] - v;   // exclusive
}

// Stage C: local exclusive scan + block offset -> row_ptr, cursor
__global__ __launch_bounds__(256) void scan_final(const int* __restrict__ degI,
                                                  const int* __restrict__ blockSums,
                                                  int* __restrict__ row_ptr,
                                                  int* __restrict__ cursor, int n, int E) {
    __shared__ int sS[256];
    int tid = threadIdx.x;
    int base = blockIdx.x * 1024 + tid * 4;
    int v[4];
    int tot = 0;
    #pragma unroll
    for (int j = 0; j < 4; j++) {
        int idx = base + j;
        int vv = (idx < n) ? degI[idx] : 0;
        v[j] = tot;
        tot += vv;
    }
    sS[tid] = tot;
    __syncthreads();
    for (int off = 1; off < 256; off <<= 1) {
        int t = (tid >= off) ? sS[tid - off] : 0;
        __syncthreads();
        sS[tid] += t;
        __syncthreads();
    }
    int tb = blockSums[blockIdx.x] + sS[tid] - tot;
    #pragma unroll
    for (int j = 0; j < 4; j++) {
        int idx = base + j;
        if (idx < n) {
            int rp = tb + v[j];
            row_ptr[idx] = rp;
            cursor[idx] = rp;
        }
    }
    if (blockIdx.x == 0 && tid == 0) row_ptr[n] = E;   // sum(in-deg) == E
}

// ---------------- norms: clamp(deg,1)^-0.5 ----------------
__global__ void norm_kernel(const int* __restrict__ degO, const int* __restrict__ degI,
                            float* __restrict__ onorm, float* __restrict__ inorm, int n) {
    int i = blockIdx.x * blockDim.x + threadIdx.x;
    if (i < n) {
        float a = (float)degO[i]; if (a < 1.f) a = 1.f;
        float b = (float)degI[i]; if (b < 1.f) b = 1.f;
        onorm[i] = rsqrtf(a);
        inorm[i] = rsqrtf(b);
    }
}

// ---------------- CSR src-value scatter ----------------
__global__ void src_scatter(const int* __restrict__ src, const int* __restrict__ dst,
                            int* __restrict__ cursor, int* __restrict__ srcs, int E) {
    int e = blockIdx.x * blockDim.x + threadIdx.x;
    if (e < E) {
        int p = atomicAdd(&cursor[dst[e]], 1);
        srcs[p] = src[e];
    }
}

__device__ __forceinline__ uint bf16rne(float f) {
    uint u = __float_as_uint(f);
    return (u + 0x7fffu + ((u >> 16) & 1u)) >> 16;
}

// ---------------- pack: fp32 * onorm -> bf16 (layer-1 input only) ----------------
__global__ __launch_bounds__(256) void pack_kernel(
        const float* __restrict__ in, const float* __restrict__ onorm,
        ushort* __restrict__ out, int total4) {
    int i = blockIdx.x * blockDim.x + threadIdx.x;
    if (i >= total4) return;
    float w = onorm[i >> 5];
    float4 v = ((const float4*)in)[i];
    ushort4 o = make_ushort4((ushort)bf16rne(v.x * w), (ushort)bf16rne(v.y * w),
                             (ushort)bf16rne(v.z * w), (ushort)bf16rne(v.w * w));
    *(ushort4*)(out + (size_t)i * 4) = o;
}

// ---------------- fused BN-apply + lrelu + onorm-fold + bf16 pack ----------------
__global__ __launch_bounds__(256) void bnpack_kernel(
        const float* __restrict__ in, ushort* __restrict__ out,
        const float* __restrict__ scale, const float* __restrict__ shift,
        const float* __restrict__ onorm, int total4) {
    int i = blockIdx.x * blockDim.x + threadIdx.x;
    if (i >= total4) return;
    int cp = (i & 31) << 2;
    float w = onorm[i >> 5];
    float4 v = ((const float4*)in)[i];
    float4 s = *(const float4*)(scale + cp);
    float4 t = *(const float4*)(shift + cp);
    float h0 = fmaf(v.x, s.x, t.x); h0 = (h0 >= 0.f) ? h0 : SLOPEV * h0;
    float h1 = fmaf(v.y, s.y, t.y); h1 = (h1 >= 0.f) ? h1 : SLOPEV * h1;
    float h2 = fmaf(v.z, s.z, t.z); h2 = (h2 >= 0.f) ? h2 : SLOPEV * h2;
    float h3 = fmaf(v.w, s.w, t.w); h3 = (h3 >= 0.f) ? h3 : SLOPEV * h3;
    ushort4 o = make_ushort4((ushort)bf16rne(h0 * w), (ushort)bf16rne(h1 * w),
                             (ushort)bf16rne(h2 * w), (ushort)bf16rne(h3 * w));
    *(ushort4*)(out + (size_t)i * 4) = o;
}

// ---------------- aggregation: one wave per dst node, bf16 rows ----------------
__global__ __launch_bounds__(256) void agg_kernel(
        const uint* __restrict__ xb, float* __restrict__ out,
        const int* __restrict__ srcs, const int* __restrict__ row_ptr,
        const float* __restrict__ inorm, int n) {
    int node = blockIdx.x * 4 + (threadIdx.x >> 6);
    if (node >= n) return;
    int lane = threadIdx.x & 63;
    int rp0 = row_ptr[node], rp1 = row_ptr[node + 1];
    float accx = 0.f, accy = 0.f;
    int j = rp0;
    for (; j + 1 < rp1; j += 2) {
        int s0 = srcs[j], s1 = srcs[j + 1];
        uint u0 = xb[(size_t)s0 * 64 + lane];
        uint u1 = xb[(size_t)s1 * 64 + lane];
        accx += __uint_as_float(u0 << 16) + __uint_as_float(u1 << 16);
        accy += __uint_as_float(u0 & 0xffff0000u) + __uint_as_float(u1 & 0xffff0000u);
    }
    if (j < rp1) {
        uint u0 = xb[(size_t)srcs[j] * 64 + lane];
        accx += __uint_as_float(u0 << 16);
        accy += __uint_as_float(u0 & 0xffff0000u);
    }
    float wi = inorm[node];
    float2 o; o.x = accx * wi; o.y = accy * wi;
    *(float2*)(out + (size_t)node * HN + lane * 2) = o;
}

// ---------------- GEMM [n,128]@[128,128]+b ----------------
// DO_STATS: col sum/sumsq atomics. DO_LRELU: epilogue lrelu.
// DO_PACK: write bf16 with onorm folded (for next agg) instead of fp32.
template<int DO_STATS, int DO_LRELU, int DO_PACK>
__global__ __launch_bounds__(256) void gemm_kernel(
        const float* __restrict__ A, const float* __restrict__ W,
        const float* __restrict__ bias, void* __restrict__ outv,
        float* __restrict__ colsum, float* __restrict__ colsq,
        const float* __restrict__ onorm, int n) {
    __shared__ float sA[64 * 132];
    int tid = threadIdx.x;
    int row0 = blockIdx.x * 64;
    for (int i = tid; i < 64 * 32; i += 256) {
        int r = i >> 5, c4 = (i & 31) << 2;
        float4 v;
        if (row0 + r < n) v = *(const float4*)(A + (size_t)(row0 + r) * HN + c4);
        else v = make_float4(0.f, 0.f, 0.f, 0.f);
        *(float4*)&sA[r * 132 + c4] = v;
    }
    __syncthreads();
    int rowg = tid >> 4, colg = tid & 15;
    int rb = rowg * 4, cb = colg * 8;
    float acc[4][8];
    #pragma unroll
    for (int r = 0; r < 4; r++)
        #pragma unroll
        for (int c = 0; c < 8; c++) acc[r][c] = 0.f;

    for (int k = 0; k < HN; k += 4) {
        float4 a4[4];
        #pragma unroll
        for (int r = 0; r < 4; r++) a4[r] = *(const float4*)&sA[(rb + r) * 132 + k];
        #pragma unroll
        for (int kk = 0; kk < 4; kk++) {
            float4 wlo = *(const float4*)(W + (size_t)(k + kk) * HN + cb);
            float4 whi = *(const float4*)(W + (size_t)(k + kk) * HN + cb + 4);
            float wv[8] = {wlo.x, wlo.y, wlo.z, wlo.w, whi.x, whi.y, whi.z, whi.w};
            #pragma unroll
            for (int r = 0; r < 4; r++) {
                float av = ((const float*)&a4[r])[kk];
                #pragma unroll
                for (int c = 0; c < 8; c++) acc[r][c] = fmaf(av, wv[c], acc[r][c]);
            }
        }
    }

    float bv[8];
    #pragma unroll
    for (int c = 0; c < 8; c++) bv[c] = bias[cb + c];
    float cs[8], cq[8];
    #pragma unroll
    for (int c = 0; c < 8; c++) { cs[c] = 0.f; cq[c] = 0.f; }

    #pragma unroll
    for (int r = 0; r < 4; r++) {
        int row = row0 + rb + r;
        if (row < n) {
            float v[8];
            #pragma unroll
            for (int c = 0; c < 8; c++) {
                float t = acc[r][c] + bv[c];
                if (DO_LRELU) t = (t >= 0.f) ? t : SLOPEV * t;
                v[c] = t;
                if (DO_STATS) { cs[c] += t; cq[c] += t * t; }
            }
            if (DO_PACK) {
                float w = onorm[row];
                ushort* o = (ushort*)outv + (size_t)row * HN + cb;
                *(ushort4*)o = make_ushort4((ushort)bf16rne(v[0] * w), (ushort)bf16rne(v[1] * w),
                                            (ushort)bf16rne(v[2] * w), (ushort)bf16rne(v[3] * w));
                *(ushort4*)(o + 4) = make_ushort4((ushort)bf16rne(v[4] * w), (ushort)bf16rne(v[5] * w),
                                                  (ushort)bf16rne(v[6] * w), (ushort)bf16rne(v[7] * w));
            } else {
                float* o = (float*)outv + (size_t)row * HN + cb;
                *(float4*)o       = make_float4(v[0], v[1], v[2], v[3]);
                *(float4*)(o + 4) = make_float4(v[4], v[5], v[6], v[7]);
            }
        }
    }

    if (DO_STATS) {
        __syncthreads();
        float* redsum = sA;
        float* redsq  = sA + 2048;
        #pragma unroll
        for (int c = 0; c < 8; c++) {
            redsum[(cb + c) * 16 + rowg] = cs[c];
            redsq [(cb + c) * 16 + rowg] = cq[c];
        }
        __syncthreads();
        if (tid < HN) {
            float s = 0.f, q = 0.f;
            #pragma unroll
            for (int j = 0; j < 16; j++) { s += redsum[tid * 16 + j]; q += redsq[tid * 16 + j]; }
            atomicAdd(&colsum[tid], s);
            atomicAdd(&colsq[tid], q);
        }
    }
}

// ---------------- BN finalize ----------------
__global__ void bn_finalize(const float* __restrict__ colsum, const float* __restrict__ colsq,
                            const float* __restrict__ gamma, const float* __restrict__ beta,
                            float* __restrict__ scale, float* __restrict__ shift, int n) {
    int c = threadIdx.x;
    if (c < HN) {
        float inv = 1.f / (float)n;
        float mean = colsum[c] * inv;
        float var = colsq[c] * inv - mean * mean;
        if (var < 0.f) var = 0.f;
        float s = gamma[c] * rsqrtf(var + EPSV);
        scale[c] = s;
        shift[c] = beta[c] - mean * s;
    }
}

// ---------------- classifier: [n,128]@[128,8]+bc ----------------
__global__ __launch_bounds__(256) void classifier_kernel(
        const float* __restrict__ A, const float* __restrict__ Wc,
        const float* __restrict__ bc, float* __restrict__ out, int n) {
    __shared__ float sW[HN * NC];
    __shared__ float sA[32 * 132];
    int tid = threadIdx.x;
    for (int i = tid; i < HN * NC; i += 256) sW[i] = Wc[i];
    int row0 = blockIdx.x * 32;
    for (int i = tid; i < 32 * 32; i += 256) {
        int r = i >> 5, c4 = (i & 31) << 2;
        float4 v = (row0 + r < n) ? *(const float4*)(A + (size_t)(row0 + r) * HN + c4)
                                  : make_float4(0.f, 0.f, 0.f, 0.f);
        *(float4*)&sA[r * 132 + c4] = v;
    }
    __syncthreads();
    int r = tid >> 3, c = tid & 7;
    float acc = 0.f;
    #pragma unroll 8
    for (int k = 0; k < HN; k++) acc = fmaf(sA[r * 132 + k], sW[k * NC + c], acc);
    int row = row0 + r;
    if (row < n) out[(size_t)row * NC + c] = acc + bc[c];
}

extern "C" void kernel_launch(void* const* d_in, const int* in_sizes, int n_in,
                              void* d_out, int out_size, void* d_ws, size_t ws_size,
                              hipStream_t stream) {
    const float* node_feat = (const float*)d_in[0];
    const int*   src    = (const int*)d_in[1];
    const int*   dst    = (const int*)d_in[2];
    const float* W1     = (const float*)d_in[3];
    const float* b1     = (const float*)d_in[4];
    const float* W2     = (const float*)d_in[5];
    const float* b2     = (const float*)d_in[6];
    const float* gamma1 = (const float*)d_in[7];
    const float* beta1  = (const float*)d_in[8];
    const float* gamma2 = (const float*)d_in[9];
    const float* beta2  = (const float*)d_in[10];
    const float* Wn1    = (const float*)d_in[11];
    const float* bn1    = (const float*)d_in[12];
    const float* Wn2    = (const float*)d_in[13];
    const float* bn2    = (const float*)d_in[14];
    const float* Wc     = (const float*)d_in[15];
    const float* bc     = (const float*)d_in[16];
    float* out = (float*)d_out;

    const int N = in_sizes[0] / HN;
    const int E = in_sizes[1];

    char* p = (char*)d_ws;
    float* bufA  = (float*)p; p += (size_t)N * HN * 4;
    float* bufB  = (float*)p; p += (size_t)N * HN * 4;
    float* onorm = (float*)p; p += (size_t)N * 4;
    float* inorm = (float*)p; p += (size_t)N * 4;
    float* scale = (float*)p; p += HN * 4;
    float* shift = (float*)p; p += HN * 4;
    char* zbase = p;
    float* cs1 = (float*)p; p += HN * 4;
    float* cq1 = (float*)p; p += HN * 4;
    float* cs2 = (float*)p; p += HN * 4;
    float* cq2 = (float*)p; p += HN * 4;
    int* degO = (int*)p; p += (size_t)N * 4;
    int* degI = (int*)p; p += (size_t)N * 4;
    size_t zbytes = (size_t)(p - zbase);
    int* row_ptr = (int*)p; p += (size_t)(N + 1) * 4;
    int* cursor  = (int*)p; p += (size_t)N * 4;
    int* blockSums = (int*)p; p += 1024 * 4;
    int* srcs    = (int*)p; p += (size_t)E * 4;
    if ((size_t)(p - (char*)d_ws) > ws_size) return;

    hipMemsetAsync(zbase, 0, zbytes, stream);

    int gE = (E + 255) / 256, gN = (N + 255) / 256;
    int nb = (N + 1023) / 1024;   // scan sections (<=1024 supported)
    deg_kernel<<<gE, 256, 0, stream>>>(src, dst, degO, degI, E);
    scan_partial<<<nb, 256, 0, stream>>>(degI, blockSums, N);
    scan_blocksums<<<1, 1024, 0, stream>>>(blockSums, nb);
    scan_final<<<nb, 256, 0, stream>>>(degI, blockSums, row_ptr, cursor, N, E);
    norm_kernel<<<gN, 256, 0, stream>>>(degO, degI, onorm, inorm, N);
    src_scatter<<<gE, 256, 0, stream>>>(src, dst, cursor, srcs, E);

    int gAgg = (N + 3) / 4;
    int gGemm = (N + 63) / 64;
    int gApply = (N * 32 + 255) / 256;

    ushort* HbA = (ushort*)bufA;
    ushort* HbB = (ushort*)bufB;

    // L1: pack(node_feat)->HbA; agg->bufB; gemm(stats)->bufA; bnpack->HbB
    pack_kernel<<<gApply, 256, 0, stream>>>(node_feat, onorm, HbA, N * 32);
    agg_kernel<<<gAgg, 256, 0, stream>>>((const uint*)HbA, bufB, srcs, row_ptr, inorm, N);
    gemm_kernel<1, 0, 0><<<gGemm, 256, 0, stream>>>(bufB, W1, b1, bufA, cs1, cq1, nullptr, N);
    bn_finalize<<<1, 128, 0, stream>>>(cs1, cq1, gamma1, beta1, scale, shift, N);
    bnpack_kernel<<<gApply, 256, 0, stream>>>(bufA, HbB, scale, shift, onorm, N * 32);

    // L2: agg->bufA; gemm(stats)->bufB; bnpack->HbA
    agg_kernel<<<gAgg, 256, 0, stream>>>((const uint*)HbB, bufA, srcs, row_ptr, inorm, N);
    gemm_kernel<1, 0, 0><<<gGemm, 256, 0, stream>>>(bufA, W2, b2, bufB, cs2, cq2, nullptr, N);
    bn_finalize<<<1, 128, 0, stream>>>(cs2, cq2, gamma2, beta2, scale, shift, N);
    bnpack_kernel<<<gApply, 256, 0, stream>>>(bufB, HbA, scale, shift, onorm, N * 32);

    // L3: agg->bufB; gemm(lrelu, pack+onorm)->HbA
    agg_kernel<<<gAgg, 256, 0, stream>>>((const uint*)HbA, bufB, srcs, row_ptr, inorm, N);
    gemm_kernel<0, 1, 1><<<gGemm, 256, 0, stream>>>(bufB, Wn1, bn1, HbA, nullptr, nullptr, onorm, N);

    // L4: agg->bufB; gemm(lrelu)->bufA; classifier
    agg_kernel<<<gAgg, 256, 0, stream>>>((const uint*)HbA, bufB, srcs, row_ptr, inorm, N);
    gemm_kernel<0, 1, 0><<<gGemm, 256, 0, stream>>>(bufB, Wn2, bn2, bufA, nullptr, nullptr, nullptr, N);
    classifier_kernel<<<(N + 31) / 32, 256, 0, stream>>>(bufA, Wc, bc, out, N);
}